// Round 1
// baseline (2373.206 us; speedup 1.0000x reference)
//
#include <hip/hip_runtime.h>
#include <hip/hip_bf16.h>
#include <stdint.h>

// DeepFakeDetectionModel: stem LN(26)->Linear(26->1024)->ReLU, 8x [LN->Linear(1024->1024)->ReLU],
// head LN->Linear(1024->1)->sigmoid.  B=65536.
//
// Strategy: fold LN gamma/beta into weights (W'=gamma*W, S'=sum W', b'=b+beta@W^T), run GEMMs on
// RAW fp16 activations, apply LN affine in the epilogue using per-row (sum,sumsq) stats produced
// by the PREVIOUS layer's epilogue (atomics). m97-style 128x128 MFMA GEMM with global_load_lds.

typedef __attribute__((ext_vector_type(8))) _Float16 f16x8;
typedef __attribute__((ext_vector_type(4))) float f32x4;

#define EPSLN 1e-5f
#define HDIM 1024

__device__ __forceinline__ void gload16(const void* g, void* l) {
  __builtin_amdgcn_global_load_lds(
      (const __attribute__((address_space(1))) unsigned int*)g,
      (__attribute__((address_space(3))) unsigned int*)l, 16, 0, 0);
}

// ---------------- zero stats ----------------
__global__ __launch_bounds__(256) void zero_f32(float* __restrict__ p, int n) {
  int i = blockIdx.x * 256 + threadIdx.x;
  if (i < n) p[i] = 0.f;
}

// ---------------- fold block weights: W'[l,o,i]=gamma*W (fp16), S'=sum(fp16 W'), b'=b+beta@W ----------------
__global__ __launch_bounds__(256) void fold_blk(
    const float* __restrict__ bg, const float* __restrict__ bb,
    const float* __restrict__ bw, const float* __restrict__ bbias,
    _Float16* __restrict__ Wf, float* __restrict__ bfold, float* __restrict__ Sfold) {
  int lo = blockIdx.x;            // layer*1024 + o
  int layer = lo >> 10;
  const float* wrow = bw + (size_t)lo * HDIM;
  const float* g = bg + (size_t)layer * HDIM;
  const float* be = bb + (size_t)layer * HDIM;
  _Float16* wout = Wf + (size_t)lo * HDIM;
  int t = threadIdx.x;
  float s = 0.f, acb = 0.f;
  for (int i = t; i < HDIM; i += 256) {
    float wv = wrow[i];
    _Float16 wp = (_Float16)(wv * g[i]);
    wout[i] = wp;
    s += (float)wp;               // S' from the ROUNDED weights (consistency with GEMM)
    acb += be[i] * wv;
  }
#pragma unroll
  for (int off = 1; off < 64; off <<= 1) { s += __shfl_xor(s, off); acb += __shfl_xor(acb, off); }
  __shared__ float rs[4], rb[4];
  int l = t & 63, w = t >> 6;
  if (l == 0) { rs[w] = s; rb[w] = acb; }
  __syncthreads();
  if (t == 0) {
    Sfold[lo] = rs[0] + rs[1] + rs[2] + rs[3];
    bfold[lo] = bbias[lo] + rb[0] + rb[1] + rb[2] + rb[3];
  }
}

// ---------------- fold head: W''=lw*lgamma (fp32), S''=sum W'', b''=lb + lbeta@lw ----------------
__global__ __launch_bounds__(256) void fold_head(
    const float* __restrict__ lg, const float* __restrict__ lb,
    const float* __restrict__ lw, const float* __restrict__ lbias,
    float* __restrict__ headW, float* __restrict__ headAux) {
  int t = threadIdx.x;
  float s = 0.f, acb = 0.f;
  for (int i = t; i < HDIM; i += 256) {
    float wp = lw[i] * lg[i];
    headW[i] = wp;
    s += wp;
    acb += lb[i] * lw[i];
  }
#pragma unroll
  for (int off = 1; off < 64; off <<= 1) { s += __shfl_xor(s, off); acb += __shfl_xor(acb, off); }
  __shared__ float rs[4], rb[4];
  int l = t & 63, w = t >> 6;
  if (l == 0) { rs[w] = s; rb[w] = acb; }
  __syncthreads();
  if (t == 0) {
    headAux[0] = rs[0] + rs[1] + rs[2] + rs[3];
    headAux[1] = lbias[0] + rb[0] + rb[1] + rb[2] + rb[3];
  }
}

// ---------------- stem: per-thread row, LN(26) + 26-dot x 1024 outs (uniform weight loads -> SMEM) ----------------
__global__ __launch_bounds__(128) void stem_kernel(
    const float* __restrict__ x, const float* __restrict__ stg, const float* __restrict__ stb,
    const float* __restrict__ stw, const float* __restrict__ stbias,
    _Float16* __restrict__ h0, float* __restrict__ stats0, int rowBase) {
  int t = threadIdx.x;
  int lrow = blockIdx.x * 128 + t;
  int grow = rowBase + lrow;
  float xr[26];
#pragma unroll
  for (int i = 0; i < 26; ++i) xr[i] = x[(size_t)grow * 26 + i];
  float m = 0.f;
#pragma unroll
  for (int i = 0; i < 26; ++i) m += xr[i];
  m *= (1.f / 26.f);
  float v = 0.f;
#pragma unroll
  for (int i = 0; i < 26; ++i) { float d = xr[i] - m; v += d * d; }
  float rstd = rsqrtf(v * (1.f / 26.f) + EPSLN);
  float xn[26];
#pragma unroll
  for (int i = 0; i < 26; ++i) xn[i] = (xr[i] - m) * rstd * stg[i] + stb[i];

  float s = 0.f, sq = 0.f;
  _Float16* hrow = h0 + (size_t)lrow * HDIM;
  for (int o = 0; o < HDIM; o += 8) {
    float a[8];
#pragma unroll
    for (int u = 0; u < 8; ++u) a[u] = stbias[o + u];
#pragma unroll
    for (int i = 0; i < 26; ++i) {
      float xv = xn[i];
#pragma unroll
      for (int u = 0; u < 8; ++u) a[u] = fmaf(xv, stw[(o + u) * 26 + i], a[u]);
    }
    f16x8 pk;
#pragma unroll
    for (int u = 0; u < 8; ++u) {
      float vv = fmaxf(a[u], 0.f);
      pk[u] = (_Float16)vv;
      s += vv; sq += vv * vv;
    }
    *(f16x8*)(hrow + o) = pk;
  }
  stats0[lrow * 2 + 0] = s;
  stats0[lrow * 2 + 1] = sq;
}

// ---------------- per-layer fused GEMM: hout = relu(rstd*(h@W'^T - mean*S') + b'), + next stats ----------------
// 128x128 tile, BK=64, 256 thr = 4 waves (2x2), each wave 64x64 via 4x4 frags of mfma 16x16x32 f16.
__global__ __launch_bounds__(256) void layer_gemm(
    const _Float16* __restrict__ hin, const float* __restrict__ stats_in,
    const _Float16* __restrict__ W, const float* __restrict__ bfold,
    const float* __restrict__ Sfold, _Float16* __restrict__ hout,
    float* __restrict__ stats_out) {
  __shared__ _Float16 As[128 * 64];
  __shared__ _Float16 Bs[128 * 64];
  const int t = threadIdx.x;
  const int l = t & 63;
  const int w = t >> 6;
  const int wm = w >> 1, wn = w & 1;
  const int brow = blockIdx.x * 128;
  const int bcol = blockIdx.y * 128;

  f32x4 acc[4][4];
#pragma unroll
  for (int i = 0; i < 4; ++i)
#pragma unroll
    for (int j = 0; j < 4; ++j) acc[i][j] = (f32x4){0.f, 0.f, 0.f, 0.f};

  // staging source: thread t loads 16B at row (q*32 + t>>3), col (t&7)*8 within the K-tile
  const _Float16* ga = hin + (size_t)(brow + (t >> 3)) * HDIM + (t & 7) * 8;
  const _Float16* gb = W + (size_t)(bcol + (t >> 3)) * HDIM + (t & 7) * 8;
  char* lA = (char*)As + (size_t)w * 1024;  // wave-uniform LDS dest base; lane adds l*16
  char* lB = (char*)Bs + (size_t)w * 1024;

  const int abyte0 = (wm * 64 + (l & 15)) * 128 + (l >> 4) * 16;
  const int bbyte0 = (wn * 64 + (l & 15)) * 128 + (l >> 4) * 16;

  for (int kt = 0; kt < 16; ++kt) {
    const _Float16* gak = ga + kt * 64;
    const _Float16* gbk = gb + kt * 64;
#pragma unroll
    for (int q = 0; q < 4; ++q) {
      gload16(gak + (size_t)q * 32 * HDIM, lA + q * 4096);
      gload16(gbk + (size_t)q * 32 * HDIM, lB + q * 4096);
    }
    __syncthreads();  // drains vmcnt -> LDS tiles ready
#pragma unroll
    for (int ks = 0; ks < 2; ++ks) {
      f16x8 af[4], bfr[4];
#pragma unroll
      for (int m = 0; m < 4; ++m)
        af[m] = *(const f16x8*)((const char*)As + abyte0 + m * 2048 + ks * 64);
#pragma unroll
      for (int n = 0; n < 4; ++n)
        bfr[n] = *(const f16x8*)((const char*)Bs + bbyte0 + n * 2048 + ks * 64);
#pragma unroll
      for (int m = 0; m < 4; ++m)
#pragma unroll
        for (int n = 0; n < 4; ++n)
          acc[m][n] = __builtin_amdgcn_mfma_f32_16x16x32_f16(af[m], bfr[n], acc[m][n], 0, 0, 0);
    }
    __syncthreads();
  }

  // epilogue: LN-affine compensation + bias + relu + fp16 store + next-layer stats
  float Sf[4], Bf[4];
#pragma unroll
  for (int n = 0; n < 4; ++n) {
    int col = bcol + wn * 64 + n * 16 + (l & 15);
    Sf[n] = Sfold[col];
    Bf[n] = bfold[col];
  }
#pragma unroll
  for (int m = 0; m < 4; ++m) {
#pragma unroll
    for (int rg = 0; rg < 4; ++rg) {
      int lrow = brow + wm * 64 + m * 16 + (l >> 4) * 4 + rg;  // C/D: col=lane&15, row=(lane>>4)*4+reg
      float sum = stats_in[lrow * 2 + 0];
      float sumsq = stats_in[lrow * 2 + 1];
      float mean = sum * (1.f / 1024.f);
      float rstd = rsqrtf(sumsq * (1.f / 1024.f) - mean * mean + EPSLN);
      float ps = 0.f, psq = 0.f;
#pragma unroll
      for (int n = 0; n < 4; ++n) {
        int col = bcol + wn * 64 + n * 16 + (l & 15);
        float vv = rstd * (acc[m][n][rg] - mean * Sf[n]) + Bf[n];
        vv = fmaxf(vv, 0.f);
        hout[(size_t)lrow * HDIM + col] = (_Float16)vv;
        ps += vv; psq += vv * vv;
      }
#pragma unroll
      for (int off = 1; off < 16; off <<= 1) {  // reduce across the 16 lanes sharing this row
        ps += __shfl_xor(ps, off);
        psq += __shfl_xor(psq, off);
      }
      if ((l & 15) == 0) {
        atomicAdd(&stats_out[lrow * 2 + 0], ps);
        atomicAdd(&stats_out[lrow * 2 + 1], psq);
      }
    }
  }
}

// ---------------- head: out = sigmoid(rstd*(h8@W'' - mean*S'') + b''), one wave per row ----------------
__global__ __launch_bounds__(512) void head_kernel(
    const _Float16* __restrict__ h8, const float* __restrict__ stats8,
    const float* __restrict__ headW, const float* __restrict__ headAux,
    float* __restrict__ out, int rowBase) {
  int t = threadIdx.x, l = t & 63, w = t >> 6;
  int lrow = blockIdx.x * 8 + w;
  const f16x8* hp = (const f16x8*)(h8 + (size_t)lrow * HDIM) + l * 2;
  f16x8 v0 = hp[0], v1 = hp[1];
  float acc = 0.f;
#pragma unroll
  for (int j = 0; j < 8; ++j) acc += (float)v0[j] * headW[l * 16 + j];
#pragma unroll
  for (int j = 0; j < 8; ++j) acc += (float)v1[j] * headW[l * 16 + 8 + j];
#pragma unroll
  for (int off = 1; off < 64; off <<= 1) acc += __shfl_xor(acc, off);
  if (l == 0) {
    float sum = stats8[lrow * 2 + 0], sumsq = stats8[lrow * 2 + 1];
    float mean = sum * (1.f / 1024.f);
    float rstd = rsqrtf(sumsq * (1.f / 1024.f) - mean * mean + EPSLN);
    float z = rstd * (acc - mean * headAux[0]) + headAux[1];
    out[rowBase + lrow] = 1.f / (1.f + expf(-z));
  }
}

extern "C" void kernel_launch(void* const* d_in, const int* in_sizes, int n_in,
                              void* d_out, int out_size, void* d_ws, size_t ws_size,
                              hipStream_t stream) {
  const float* x      = (const float*)d_in[0];
  const float* stg    = (const float*)d_in[1];
  const float* stb    = (const float*)d_in[2];
  const float* stw    = (const float*)d_in[3];
  const float* stbias = (const float*)d_in[4];
  const float* bg     = (const float*)d_in[5];
  const float* bb     = (const float*)d_in[6];
  const float* bw     = (const float*)d_in[7];
  const float* bbias  = (const float*)d_in[8];
  const float* lg     = (const float*)d_in[9];
  const float* lb     = (const float*)d_in[10];
  const float* lw     = (const float*)d_in[11];
  const float* lbias  = (const float*)d_in[12];
  float* out = (float*)d_out;
  const int B = 65536;
  const int L = 8;

  char* ws = (char*)d_ws;
  size_t off = 0;
  auto carve = [&](size_t bytes) -> char* {
    char* p = ws + off;
    off = (off + bytes + 255) & ~(size_t)255;
    return p;
  };
  _Float16* Wf   = (_Float16*)carve((size_t)L * HDIM * HDIM * 2);
  float* bfold   = (float*)carve((size_t)L * HDIM * 4);
  float* Sfold   = (float*)carve((size_t)L * HDIM * 4);
  float* headW   = (float*)carve((size_t)HDIM * 4);
  float* headAux = (float*)carve(256);
  size_t fixed = off;

  // pick largest batch chunk R (power of 2, >=256) whose buffers fit in ws
  int R = B;
  while (R > 256) {
    size_t need = fixed + 2 * ((size_t)R * HDIM * 2 + 256) + ((size_t)9 * R * 2 * 4 + 256);
    if (need <= ws_size) break;
    R >>= 1;
  }
  _Float16* hA = (_Float16*)carve((size_t)R * HDIM * 2);
  _Float16* hB = (_Float16*)carve((size_t)R * HDIM * 2);
  float* stats = (float*)carve((size_t)9 * R * 2 * 4);  // 9 slots: h0..h8 (sum,sumsq)

  fold_blk<<<L * HDIM, 256, 0, stream>>>(bg, bb, bw, bbias, Wf, bfold, Sfold);
  fold_head<<<1, 256, 0, stream>>>(lg, lb, lw, lbias, headW, headAux);

  const int nstats = 9 * R * 2;
  for (int c = 0; c < B / R; ++c) {
    int rowBase = c * R;
    zero_f32<<<(nstats + 255) / 256, 256, 0, stream>>>(stats, nstats);
    stem_kernel<<<R / 128, 128, 0, stream>>>(x, stg, stb, stw, stbias, hA, stats, rowBase);
    _Float16* cur = hA;
    _Float16* nxt = hB;
    for (int lyr = 0; lyr < L; ++lyr) {
      dim3 grid(R / 128, 8);
      layer_gemm<<<grid, 256, 0, stream>>>(
          cur, stats + (size_t)lyr * R * 2, Wf + (size_t)lyr * HDIM * HDIM,
          bfold + lyr * HDIM, Sfold + lyr * HDIM, nxt, stats + (size_t)(lyr + 1) * R * 2);
      _Float16* tmp = cur; cur = nxt; nxt = tmp;
    }
    head_kernel<<<R / 8, 512, 0, stream>>>(cur, stats + (size_t)8 * R * 2, headW, headAux, out, rowBase);
  }
}

// Round 2
// 1965.371 us; speedup vs baseline: 1.2075x; 1.2075x over previous
//
#include <hip/hip_runtime.h>
#include <hip/hip_bf16.h>
#include <stdint.h>

// DeepFakeDetectionModel: stem LN(26)->Linear(26->1024)->ReLU, 8x [LN->Linear(1024->1024)->ReLU],
// head LN->Linear(1024->1)->sigmoid.  B=65536.
//
// Strategy: fold LN gamma/beta into weights (W'=gamma*W, S'=sum W', b'=b+beta@W^T), run GEMMs on
// RAW fp16 activations, apply LN affine in the epilogue using per-row (sum,sumsq) stats produced
// by the PREVIOUS layer's epilogue (atomics). m97-style 128x128 MFMA GEMM with global_load_lds.
// R1: stem rebuilt as LN-prepass (fp16, K padded to 64) + one-K-tile MFMA GEMM with coalesced I/O
//     (old stem was latency-bound at 330us/chunk: per-thread row writes, 6% occupancy).

typedef __attribute__((ext_vector_type(8))) _Float16 f16x8;
typedef __attribute__((ext_vector_type(4))) float f32x4;

#define EPSLN 1e-5f
#define HDIM 1024

__device__ __forceinline__ void gload16(const void* g, void* l) {
  __builtin_amdgcn_global_load_lds(
      (const __attribute__((address_space(1))) unsigned int*)g,
      (__attribute__((address_space(3))) unsigned int*)l, 16, 0, 0);
}

// ---------------- zero stats ----------------
__global__ __launch_bounds__(256) void zero_f32(float* __restrict__ p, int n) {
  int i = blockIdx.x * 256 + threadIdx.x;
  if (i < n) p[i] = 0.f;
}

// ---------------- fold block weights: W'[l,o,i]=gamma*W (fp16), S'=sum(fp16 W'), b'=b+beta@W ----------------
__global__ __launch_bounds__(256) void fold_blk(
    const float* __restrict__ bg, const float* __restrict__ bb,
    const float* __restrict__ bw, const float* __restrict__ bbias,
    _Float16* __restrict__ Wf, float* __restrict__ bfold, float* __restrict__ Sfold) {
  int lo = blockIdx.x;            // layer*1024 + o
  int layer = lo >> 10;
  const float* wrow = bw + (size_t)lo * HDIM;
  const float* g = bg + (size_t)layer * HDIM;
  const float* be = bb + (size_t)layer * HDIM;
  _Float16* wout = Wf + (size_t)lo * HDIM;
  int t = threadIdx.x;
  float s = 0.f, acb = 0.f;
  for (int i = t; i < HDIM; i += 256) {
    float wv = wrow[i];
    _Float16 wp = (_Float16)(wv * g[i]);
    wout[i] = wp;
    s += (float)wp;               // S' from the ROUNDED weights (consistency with GEMM)
    acb += be[i] * wv;
  }
#pragma unroll
  for (int off = 1; off < 64; off <<= 1) { s += __shfl_xor(s, off); acb += __shfl_xor(acb, off); }
  __shared__ float rs[4], rb[4];
  int l = t & 63, w = t >> 6;
  if (l == 0) { rs[w] = s; rb[w] = acb; }
  __syncthreads();
  if (t == 0) {
    Sfold[lo] = rs[0] + rs[1] + rs[2] + rs[3];
    bfold[lo] = bbias[lo] + rb[0] + rb[1] + rb[2] + rb[3];
  }
}

// ---------------- fold head: W''=lw*lgamma (fp32), S''=sum W'', b''=lb + lbeta@lw ----------------
__global__ __launch_bounds__(256) void fold_head(
    const float* __restrict__ lg, const float* __restrict__ lb,
    const float* __restrict__ lw, const float* __restrict__ lbias,
    float* __restrict__ headW, float* __restrict__ headAux) {
  int t = threadIdx.x;
  float s = 0.f, acb = 0.f;
  for (int i = t; i < HDIM; i += 256) {
    float wp = lw[i] * lg[i];
    headW[i] = wp;
    s += wp;
    acb += lb[i] * lw[i];
  }
#pragma unroll
  for (int off = 1; off < 64; off <<= 1) { s += __shfl_xor(s, off); acb += __shfl_xor(acb, off); }
  __shared__ float rs[4], rb[4];
  int l = t & 63, w = t >> 6;
  if (l == 0) { rs[w] = s; rb[w] = acb; }
  __syncthreads();
  if (t == 0) {
    headAux[0] = rs[0] + rs[1] + rs[2] + rs[3];
    headAux[1] = lbias[0] + rb[0] + rb[1] + rb[2] + rb[3];
  }
}

// ---------------- stem weight pad+cast: Wst[o][0:64] fp16, cols >=26 zero ----------------
__global__ __launch_bounds__(256) void fold_stem(const float* __restrict__ stw,
                                                 _Float16* __restrict__ Wst) {
  int idx = blockIdx.x * 256 + threadIdx.x;   // 1024*64
  int o = idx >> 6, i = idx & 63;
  Wst[idx] = (i < 26) ? (_Float16)stw[o * 26 + i] : (_Float16)0.f;
}

// ---------------- stem prepass: LN(26) with gamma/beta -> xn fp16 [rows][64], zero-padded ----------------
// 256 threads, 128 rows/block. Coalesced flat load -> LDS, per-thread LN, LDS -> coalesced flat store.
__global__ __launch_bounds__(256) void stem_prep(
    const float* __restrict__ x, const float* __restrict__ stg, const float* __restrict__ stb,
    _Float16* __restrict__ xn, int rowBase) {
  __shared__ float xin[128 * 26];
  __shared__ _Float16 xo[128 * 64];
  int t = threadIdx.x;
  const float* src = x + ((size_t)rowBase + (size_t)blockIdx.x * 128) * 26;
  for (int i = t; i < 128 * 26; i += 256) xin[i] = src[i];
  __syncthreads();
  if (t < 128) {
    float m = 0.f;
#pragma unroll
    for (int i = 0; i < 26; ++i) m += xin[t * 26 + i];
    m *= (1.f / 26.f);
    float v = 0.f;
#pragma unroll
    for (int i = 0; i < 26; ++i) { float d = xin[t * 26 + i] - m; v += d * d; }
    float rstd = rsqrtf(v * (1.f / 26.f) + EPSLN);
    _Float16* orow = xo + t * 64;
#pragma unroll
    for (int i = 0; i < 26; ++i)
      orow[i] = (_Float16)((xin[t * 26 + i] - m) * rstd * stg[i] + stb[i]);
#pragma unroll
    for (int i = 26; i < 64; ++i) orow[i] = (_Float16)0.f;
  }
  __syncthreads();
  const float4* s4 = (const float4*)xo;                       // 128*64*2/16 = 1024 vec4
  float4* d4 = (float4*)(xn + (size_t)blockIdx.x * 128 * 64);
  for (int i = t; i < 1024; i += 256) d4[i] = s4[i];
}

// ---------------- stem GEMM: h0 = relu(xn @ Wst^T + stbias), K=64 (one tile), + stats ----------------
__global__ __launch_bounds__(256) void stem_gemm(
    const _Float16* __restrict__ xn, const _Float16* __restrict__ Wst,
    const float* __restrict__ stbias, _Float16* __restrict__ hout,
    float* __restrict__ stats_out) {
  __shared__ _Float16 As[128 * 64];
  __shared__ _Float16 Bs[128 * 64];
  const int t = threadIdx.x;
  const int l = t & 63;
  const int w = t >> 6;
  const int wm = w >> 1, wn = w & 1;
  const int brow = blockIdx.x * 128;
  const int bcol = blockIdx.y * 128;

  f32x4 acc[4][4];
#pragma unroll
  for (int i = 0; i < 4; ++i)
#pragma unroll
    for (int j = 0; j < 4; ++j) acc[i][j] = (f32x4){0.f, 0.f, 0.f, 0.f};

  const _Float16* ga = xn + (size_t)(brow + (t >> 3)) * 64 + (t & 7) * 8;
  const _Float16* gb = Wst + (size_t)(bcol + (t >> 3)) * 64 + (t & 7) * 8;
  char* lA = (char*)As + (size_t)w * 1024;
  char* lB = (char*)Bs + (size_t)w * 1024;
#pragma unroll
  for (int q = 0; q < 4; ++q) {
    gload16(ga + (size_t)q * 32 * 64, lA + q * 4096);
    gload16(gb + (size_t)q * 32 * 64, lB + q * 4096);
  }
  __syncthreads();

  const int abyte0 = (wm * 64 + (l & 15)) * 128 + (l >> 4) * 16;
  const int bbyte0 = (wn * 64 + (l & 15)) * 128 + (l >> 4) * 16;
#pragma unroll
  for (int ks = 0; ks < 2; ++ks) {
    f16x8 af[4], bfr[4];
#pragma unroll
    for (int m = 0; m < 4; ++m)
      af[m] = *(const f16x8*)((const char*)As + abyte0 + m * 2048 + ks * 64);
#pragma unroll
    for (int n = 0; n < 4; ++n)
      bfr[n] = *(const f16x8*)((const char*)Bs + bbyte0 + n * 2048 + ks * 64);
#pragma unroll
    for (int m = 0; m < 4; ++m)
#pragma unroll
      for (int n = 0; n < 4; ++n)
        acc[m][n] = __builtin_amdgcn_mfma_f32_16x16x32_f16(af[m], bfr[n], acc[m][n], 0, 0, 0);
  }

  float Bf[4];
#pragma unroll
  for (int n = 0; n < 4; ++n) Bf[n] = stbias[bcol + wn * 64 + n * 16 + (l & 15)];
#pragma unroll
  for (int m = 0; m < 4; ++m) {
#pragma unroll
    for (int rg = 0; rg < 4; ++rg) {
      int lrow = brow + wm * 64 + m * 16 + (l >> 4) * 4 + rg;
      float ps = 0.f, psq = 0.f;
#pragma unroll
      for (int n = 0; n < 4; ++n) {
        int col = bcol + wn * 64 + n * 16 + (l & 15);
        float vv = fmaxf(acc[m][n][rg] + Bf[n], 0.f);
        hout[(size_t)lrow * HDIM + col] = (_Float16)vv;
        ps += vv; psq += vv * vv;
      }
#pragma unroll
      for (int off = 1; off < 16; off <<= 1) {
        ps += __shfl_xor(ps, off);
        psq += __shfl_xor(psq, off);
      }
      if ((l & 15) == 0) {
        atomicAdd(&stats_out[lrow * 2 + 0], ps);
        atomicAdd(&stats_out[lrow * 2 + 1], psq);
      }
    }
  }
}

// ---------------- per-layer fused GEMM: hout = relu(rstd*(h@W'^T - mean*S') + b'), + next stats ----------------
// 128x128 tile, BK=64, 256 thr = 4 waves (2x2), each wave 64x64 via 4x4 frags of mfma 16x16x32 f16.
__global__ __launch_bounds__(256) void layer_gemm(
    const _Float16* __restrict__ hin, const float* __restrict__ stats_in,
    const _Float16* __restrict__ W, const float* __restrict__ bfold,
    const float* __restrict__ Sfold, _Float16* __restrict__ hout,
    float* __restrict__ stats_out) {
  __shared__ _Float16 As[128 * 64];
  __shared__ _Float16 Bs[128 * 64];
  const int t = threadIdx.x;
  const int l = t & 63;
  const int w = t >> 6;
  const int wm = w >> 1, wn = w & 1;
  const int brow = blockIdx.x * 128;
  const int bcol = blockIdx.y * 128;

  f32x4 acc[4][4];
#pragma unroll
  for (int i = 0; i < 4; ++i)
#pragma unroll
    for (int j = 0; j < 4; ++j) acc[i][j] = (f32x4){0.f, 0.f, 0.f, 0.f};

  // staging source: thread t loads 16B at row (q*32 + t>>3), col (t&7)*8 within the K-tile
  const _Float16* ga = hin + (size_t)(brow + (t >> 3)) * HDIM + (t & 7) * 8;
  const _Float16* gb = W + (size_t)(bcol + (t >> 3)) * HDIM + (t & 7) * 8;
  char* lA = (char*)As + (size_t)w * 1024;  // wave-uniform LDS dest base; lane adds l*16
  char* lB = (char*)Bs + (size_t)w * 1024;

  const int abyte0 = (wm * 64 + (l & 15)) * 128 + (l >> 4) * 16;
  const int bbyte0 = (wn * 64 + (l & 15)) * 128 + (l >> 4) * 16;

  for (int kt = 0; kt < 16; ++kt) {
    const _Float16* gak = ga + kt * 64;
    const _Float16* gbk = gb + kt * 64;
#pragma unroll
    for (int q = 0; q < 4; ++q) {
      gload16(gak + (size_t)q * 32 * HDIM, lA + q * 4096);
      gload16(gbk + (size_t)q * 32 * HDIM, lB + q * 4096);
    }
    __syncthreads();  // drains vmcnt -> LDS tiles ready
#pragma unroll
    for (int ks = 0; ks < 2; ++ks) {
      f16x8 af[4], bfr[4];
#pragma unroll
      for (int m = 0; m < 4; ++m)
        af[m] = *(const f16x8*)((const char*)As + abyte0 + m * 2048 + ks * 64);
#pragma unroll
      for (int n = 0; n < 4; ++n)
        bfr[n] = *(const f16x8*)((const char*)Bs + bbyte0 + n * 2048 + ks * 64);
#pragma unroll
      for (int m = 0; m < 4; ++m)
#pragma unroll
        for (int n = 0; n < 4; ++n)
          acc[m][n] = __builtin_amdgcn_mfma_f32_16x16x32_f16(af[m], bfr[n], acc[m][n], 0, 0, 0);
    }
    __syncthreads();
  }

  // epilogue: LN-affine compensation + bias + relu + fp16 store + next-layer stats
  float Sf[4], Bf[4];
#pragma unroll
  for (int n = 0; n < 4; ++n) {
    int col = bcol + wn * 64 + n * 16 + (l & 15);
    Sf[n] = Sfold[col];
    Bf[n] = bfold[col];
  }
#pragma unroll
  for (int m = 0; m < 4; ++m) {
#pragma unroll
    for (int rg = 0; rg < 4; ++rg) {
      int lrow = brow + wm * 64 + m * 16 + (l >> 4) * 4 + rg;  // C/D: col=lane&15, row=(lane>>4)*4+reg
      float sum = stats_in[lrow * 2 + 0];
      float sumsq = stats_in[lrow * 2 + 1];
      float mean = sum * (1.f / 1024.f);
      float rstd = rsqrtf(sumsq * (1.f / 1024.f) - mean * mean + EPSLN);
      float ps = 0.f, psq = 0.f;
#pragma unroll
      for (int n = 0; n < 4; ++n) {
        int col = bcol + wn * 64 + n * 16 + (l & 15);
        float vv = rstd * (acc[m][n][rg] - mean * Sf[n]) + Bf[n];
        vv = fmaxf(vv, 0.f);
        hout[(size_t)lrow * HDIM + col] = (_Float16)vv;
        ps += vv; psq += vv * vv;
      }
#pragma unroll
      for (int off = 1; off < 16; off <<= 1) {  // reduce across the 16 lanes sharing this row
        ps += __shfl_xor(ps, off);
        psq += __shfl_xor(psq, off);
      }
      if ((l & 15) == 0) {
        atomicAdd(&stats_out[lrow * 2 + 0], ps);
        atomicAdd(&stats_out[lrow * 2 + 1], psq);
      }
    }
  }
}

// ---------------- head: out = sigmoid(rstd*(h8@W'' - mean*S'') + b''), one wave per row ----------------
__global__ __launch_bounds__(512) void head_kernel(
    const _Float16* __restrict__ h8, const float* __restrict__ stats8,
    const float* __restrict__ headW, const float* __restrict__ headAux,
    float* __restrict__ out, int rowBase) {
  int t = threadIdx.x, l = t & 63, w = t >> 6;
  int lrow = blockIdx.x * 8 + w;
  const f16x8* hp = (const f16x8*)(h8 + (size_t)lrow * HDIM) + l * 2;
  f16x8 v0 = hp[0], v1 = hp[1];
  float acc = 0.f;
#pragma unroll
  for (int j = 0; j < 8; ++j) acc += (float)v0[j] * headW[l * 16 + j];
#pragma unroll
  for (int j = 0; j < 8; ++j) acc += (float)v1[j] * headW[l * 16 + 8 + j];
#pragma unroll
  for (int off = 1; off < 64; off <<= 1) acc += __shfl_xor(acc, off);
  if (l == 0) {
    float sum = stats8[lrow * 2 + 0], sumsq = stats8[lrow * 2 + 1];
    float mean = sum * (1.f / 1024.f);
    float rstd = rsqrtf(sumsq * (1.f / 1024.f) - mean * mean + EPSLN);
    float z = rstd * (acc - mean * headAux[0]) + headAux[1];
    out[rowBase + lrow] = 1.f / (1.f + expf(-z));
  }
}

extern "C" void kernel_launch(void* const* d_in, const int* in_sizes, int n_in,
                              void* d_out, int out_size, void* d_ws, size_t ws_size,
                              hipStream_t stream) {
  const float* x      = (const float*)d_in[0];
  const float* stg    = (const float*)d_in[1];
  const float* stb    = (const float*)d_in[2];
  const float* stw    = (const float*)d_in[3];
  const float* stbias = (const float*)d_in[4];
  const float* bg     = (const float*)d_in[5];
  const float* bb     = (const float*)d_in[6];
  const float* bw     = (const float*)d_in[7];
  const float* bbias  = (const float*)d_in[8];
  const float* lg     = (const float*)d_in[9];
  const float* lb     = (const float*)d_in[10];
  const float* lw     = (const float*)d_in[11];
  const float* lbias  = (const float*)d_in[12];
  float* out = (float*)d_out;
  const int B = 65536;
  const int L = 8;

  char* ws = (char*)d_ws;
  size_t off = 0;
  auto carve = [&](size_t bytes) -> char* {
    char* p = ws + off;
    off = (off + bytes + 255) & ~(size_t)255;
    return p;
  };
  _Float16* Wf   = (_Float16*)carve((size_t)L * HDIM * HDIM * 2);
  float* bfold   = (float*)carve((size_t)L * HDIM * 4);
  float* Sfold   = (float*)carve((size_t)L * HDIM * 4);
  float* headW   = (float*)carve((size_t)HDIM * 4);
  float* headAux = (float*)carve(256);
  _Float16* Wst  = (_Float16*)carve((size_t)HDIM * 64 * 2);
  size_t fixed = off;

  // pick largest batch chunk R (power of 2, >=256) whose buffers fit in ws
  int R = B;
  while (R > 256) {
    size_t need = fixed + 2 * ((size_t)R * HDIM * 2 + 256) + ((size_t)9 * R * 2 * 4 + 256)
                  + ((size_t)R * 64 * 2 + 256);
    if (need <= ws_size) break;
    R >>= 1;
  }
  _Float16* hA = (_Float16*)carve((size_t)R * HDIM * 2);
  _Float16* hB = (_Float16*)carve((size_t)R * HDIM * 2);
  float* stats = (float*)carve((size_t)9 * R * 2 * 4);  // 9 slots: h0..h8 (sum,sumsq)
  _Float16* xnb = (_Float16*)carve((size_t)R * 64 * 2);

  fold_blk<<<L * HDIM, 256, 0, stream>>>(bg, bb, bw, bbias, Wf, bfold, Sfold);
  fold_head<<<1, 256, 0, stream>>>(lg, lb, lw, lbias, headW, headAux);
  fold_stem<<<HDIM * 64 / 256, 256, 0, stream>>>(stw, Wst);

  const int nstats = 9 * R * 2;
  for (int c = 0; c < B / R; ++c) {
    int rowBase = c * R;
    zero_f32<<<(nstats + 255) / 256, 256, 0, stream>>>(stats, nstats);
    stem_prep<<<R / 128, 256, 0, stream>>>(x, stg, stb, xnb, rowBase);
    {
      dim3 grid(R / 128, 8);
      stem_gemm<<<grid, 256, 0, stream>>>(xnb, Wst, stbias, hA, stats);
    }
    _Float16* cur = hA;
    _Float16* nxt = hB;
    for (int lyr = 0; lyr < L; ++lyr) {
      dim3 grid(R / 128, 8);
      layer_gemm<<<grid, 256, 0, stream>>>(
          cur, stats + (size_t)lyr * R * 2, Wf + (size_t)lyr * HDIM * HDIM,
          bfold + lyr * HDIM, Sfold + lyr * HDIM, nxt, stats + (size_t)(lyr + 1) * R * 2);
      _Float16* tmp = cur; cur = nxt; nxt = tmp;
    }
    head_kernel<<<R / 8, 512, 0, stream>>>(cur, stats + (size_t)8 * R * 2, headW, headAux, out, rowBase);
  }
}

// Round 3
// 1495.554 us; speedup vs baseline: 1.5868x; 1.3141x over previous
//
#include <hip/hip_runtime.h>
#include <hip/hip_bf16.h>
#include <stdint.h>

// DeepFakeDetectionModel: stem LN(26)->Linear(26->1024)->ReLU, 8x [LN->Linear(1024->1024)->ReLU],
// head LN->Linear(1024->1)->sigmoid.  B=65536.
//
// LN folded into weights (W'=gamma*W fp16, S'=sum W', b'=b+beta@W^T); GEMMs run on RAW fp16
// activations; LN affine applied in epilogue from per-row (sum,sumsq) stats produced by the
// previous layer's epilogue.
// R2: layer_gemm ported to the 256x256 8-phase schedule (T2 swizzle + T3/T4 counted-wait phases
//     + T5 setprio + T1-ish block ordering). Old 128^2 single-buffer loop was 16-way bank
//     conflicted (2.5e7 conflict cycles) and serialized stage->compute.

typedef __attribute__((ext_vector_type(8))) _Float16 f16x8;
typedef __attribute__((ext_vector_type(4))) float f32x4;

#define EPSLN 1e-5f
#define HDIM 1024

__device__ __forceinline__ void gload16(const void* g, void* l) {
  __builtin_amdgcn_global_load_lds(
      (const __attribute__((address_space(1))) unsigned int*)g,
      (__attribute__((address_space(3))) unsigned int*)l, 16, 0, 0);
}

// ---------------- zero stats ----------------
__global__ __launch_bounds__(256) void zero_f32(float* __restrict__ p, int n) {
  int i = blockIdx.x * 256 + threadIdx.x;
  if (i < n) p[i] = 0.f;
}

// ---------------- fold block weights ----------------
__global__ __launch_bounds__(256) void fold_blk(
    const float* __restrict__ bg, const float* __restrict__ bb,
    const float* __restrict__ bw, const float* __restrict__ bbias,
    _Float16* __restrict__ Wf, float* __restrict__ bfold, float* __restrict__ Sfold) {
  int lo = blockIdx.x;            // layer*1024 + o
  int layer = lo >> 10;
  const float* wrow = bw + (size_t)lo * HDIM;
  const float* g = bg + (size_t)layer * HDIM;
  const float* be = bb + (size_t)layer * HDIM;
  _Float16* wout = Wf + (size_t)lo * HDIM;
  int t = threadIdx.x;
  float s = 0.f, acb = 0.f;
  for (int i = t; i < HDIM; i += 256) {
    float wv = wrow[i];
    _Float16 wp = (_Float16)(wv * g[i]);
    wout[i] = wp;
    s += (float)wp;               // S' from ROUNDED weights (consistency with GEMM)
    acb += be[i] * wv;
  }
#pragma unroll
  for (int off = 1; off < 64; off <<= 1) { s += __shfl_xor(s, off); acb += __shfl_xor(acb, off); }
  __shared__ float rs[4], rb[4];
  int l = t & 63, w = t >> 6;
  if (l == 0) { rs[w] = s; rb[w] = acb; }
  __syncthreads();
  if (t == 0) {
    Sfold[lo] = rs[0] + rs[1] + rs[2] + rs[3];
    bfold[lo] = bbias[lo] + rb[0] + rb[1] + rb[2] + rb[3];
  }
}

// ---------------- fold head ----------------
__global__ __launch_bounds__(256) void fold_head(
    const float* __restrict__ lg, const float* __restrict__ lb,
    const float* __restrict__ lw, const float* __restrict__ lbias,
    float* __restrict__ headW, float* __restrict__ headAux) {
  int t = threadIdx.x;
  float s = 0.f, acb = 0.f;
  for (int i = t; i < HDIM; i += 256) {
    float wp = lw[i] * lg[i];
    headW[i] = wp;
    s += wp;
    acb += lb[i] * lw[i];
  }
#pragma unroll
  for (int off = 1; off < 64; off <<= 1) { s += __shfl_xor(s, off); acb += __shfl_xor(acb, off); }
  __shared__ float rs[4], rb[4];
  int l = t & 63, w = t >> 6;
  if (l == 0) { rs[w] = s; rb[w] = acb; }
  __syncthreads();
  if (t == 0) {
    headAux[0] = rs[0] + rs[1] + rs[2] + rs[3];
    headAux[1] = lbias[0] + rb[0] + rb[1] + rb[2] + rb[3];
  }
}

// ---------------- stem weight pad+cast ----------------
__global__ __launch_bounds__(256) void fold_stem(const float* __restrict__ stw,
                                                 _Float16* __restrict__ Wst) {
  int idx = blockIdx.x * 256 + threadIdx.x;   // 1024*64
  int o = idx >> 6, i = idx & 63;
  Wst[idx] = (i < 26) ? (_Float16)stw[o * 26 + i] : (_Float16)0.f;
}

// ---------------- stem prepass: LN(26) -> xn fp16 [rows][64], zero-padded ----------------
__global__ __launch_bounds__(256) void stem_prep(
    const float* __restrict__ x, const float* __restrict__ stg, const float* __restrict__ stb,
    _Float16* __restrict__ xn, int rowBase) {
  __shared__ float xin[128 * 26];
  __shared__ _Float16 xo[128 * 64];
  int t = threadIdx.x;
  const float* src = x + ((size_t)rowBase + (size_t)blockIdx.x * 128) * 26;
  for (int i = t; i < 128 * 26; i += 256) xin[i] = src[i];
  __syncthreads();
  if (t < 128) {
    float m = 0.f;
#pragma unroll
    for (int i = 0; i < 26; ++i) m += xin[t * 26 + i];
    m *= (1.f / 26.f);
    float v = 0.f;
#pragma unroll
    for (int i = 0; i < 26; ++i) { float d = xin[t * 26 + i] - m; v += d * d; }
    float rstd = rsqrtf(v * (1.f / 26.f) + EPSLN);
    _Float16* orow = xo + t * 64;
#pragma unroll
    for (int i = 0; i < 26; ++i)
      orow[i] = (_Float16)((xin[t * 26 + i] - m) * rstd * stg[i] + stb[i]);
#pragma unroll
    for (int i = 26; i < 64; ++i) orow[i] = (_Float16)0.f;
  }
  __syncthreads();
  const float4* s4 = (const float4*)xo;
  float4* d4 = (float4*)(xn + (size_t)blockIdx.x * 128 * 64);
  for (int i = t; i < 1024; i += 256) d4[i] = s4[i];
}

// ---------------- stem GEMM: h0 = relu(xn @ Wst^T + stbias), K=64, + stats ----------------
__global__ __launch_bounds__(256) void stem_gemm(
    const _Float16* __restrict__ xn, const _Float16* __restrict__ Wst,
    const float* __restrict__ stbias, _Float16* __restrict__ hout,
    float* __restrict__ stats_out) {
  __shared__ _Float16 As[128 * 64];
  __shared__ _Float16 Bs[128 * 64];
  const int t = threadIdx.x;
  const int l = t & 63;
  const int w = t >> 6;
  const int wm = w >> 1, wn = w & 1;
  const int brow = blockIdx.x * 128;
  const int bcol = blockIdx.y * 128;

  f32x4 acc[4][4];
#pragma unroll
  for (int i = 0; i < 4; ++i)
#pragma unroll
    for (int j = 0; j < 4; ++j) acc[i][j] = (f32x4){0.f, 0.f, 0.f, 0.f};

  const _Float16* ga = xn + (size_t)(brow + (t >> 3)) * 64 + (t & 7) * 8;
  const _Float16* gb = Wst + (size_t)(bcol + (t >> 3)) * 64 + (t & 7) * 8;
  char* lA = (char*)As + (size_t)w * 1024;
  char* lB = (char*)Bs + (size_t)w * 1024;
#pragma unroll
  for (int q = 0; q < 4; ++q) {
    gload16(ga + (size_t)q * 32 * 64, lA + q * 4096);
    gload16(gb + (size_t)q * 32 * 64, lB + q * 4096);
  }
  __syncthreads();

  const int abyte0 = (wm * 64 + (l & 15)) * 128 + (l >> 4) * 16;
  const int bbyte0 = (wn * 64 + (l & 15)) * 128 + (l >> 4) * 16;
#pragma unroll
  for (int ks = 0; ks < 2; ++ks) {
    f16x8 af[4], bfr[4];
#pragma unroll
    for (int m = 0; m < 4; ++m)
      af[m] = *(const f16x8*)((const char*)As + abyte0 + m * 2048 + ks * 64);
#pragma unroll
    for (int n = 0; n < 4; ++n)
      bfr[n] = *(const f16x8*)((const char*)Bs + bbyte0 + n * 2048 + ks * 64);
#pragma unroll
    for (int m = 0; m < 4; ++m)
#pragma unroll
      for (int n = 0; n < 4; ++n)
        acc[m][n] = __builtin_amdgcn_mfma_f32_16x16x32_f16(af[m], bfr[n], acc[m][n], 0, 0, 0);
  }

  float Bf[4];
#pragma unroll
  for (int n = 0; n < 4; ++n) Bf[n] = stbias[bcol + wn * 64 + n * 16 + (l & 15)];
#pragma unroll
  for (int m = 0; m < 4; ++m) {
#pragma unroll
    for (int rg = 0; rg < 4; ++rg) {
      int lrow = brow + wm * 64 + m * 16 + (l >> 4) * 4 + rg;
      float ps = 0.f, psq = 0.f;
#pragma unroll
      for (int n = 0; n < 4; ++n) {
        int col = bcol + wn * 64 + n * 16 + (l & 15);
        float vv = fmaxf(acc[m][n][rg] + Bf[n], 0.f);
        hout[(size_t)lrow * HDIM + col] = (_Float16)vv;
        ps += vv; psq += vv * vv;
      }
#pragma unroll
      for (int off = 1; off < 16; off <<= 1) {
        ps += __shfl_xor(ps, off);
        psq += __shfl_xor(psq, off);
      }
      if ((l & 15) == 0) {
        atomicAdd(&stats_out[lrow * 2 + 0], ps);
        atomicAdd(&stats_out[lrow * 2 + 1], psq);
      }
    }
  }
}

// ---------------- per-layer fused GEMM, 256x256 8-phase schedule ----------------
// 512 thr = 8 waves (2M x 4N); per-wave 128x64 output = acc[8][4] of 16x16x32 f16 MFMA.
// LDS: 2 K-tile buffers x (A 32KB + B 32KB) = 128KB -> 1 block/CU, 2 waves/SIMD.
// Per K-tile: 4 quadrant phases {ds_read | stage-issue -> s_barrier -> lgkmcnt(0) ->
// setprio(1) 16 MFMA setprio(0) -> barrier}; per-wave vmcnt(0) aged 2-3 phases before the
// K-tile's last barrier (loads stay in flight across phases; never drain right after issue).
// LDS bank swizzle: chunk c ^= (row&7) applied on the *global source* (gload_lds dest must
// stay linear) and on the ds_read address -> 8 lanes per 4-bank group (b128 optimum).
__global__ __launch_bounds__(512, 2) void layer_gemm(
    const _Float16* __restrict__ hin, const float* __restrict__ stats_in,
    const _Float16* __restrict__ W, const float* __restrict__ bfold,
    const float* __restrict__ Sfold, _Float16* __restrict__ hout,
    float* __restrict__ stats_out) {
  __shared__ __align__(128) char smem[2 * 65536];  // [par][A 32KB | B 32KB]
  const int t = threadIdx.x;
  const int l = t & 63;
  const int w = t >> 6;
  const int wm = w >> 2, wn = w & 3;
  const int bid = blockIdx.x;
  const int brow = (bid >> 2) * 256;   // consecutive bids share the A-panel (temporal locality)
  const int bcol = (bid & 3) * 256;

  f32x4 acc[8][4];
#pragma unroll
  for (int i = 0; i < 8; ++i)
#pragma unroll
    for (int j = 0; j < 4; ++j) acc[i][j] = (f32x4){0.f, 0.f, 0.f, 0.f};

  // staging: per half-tile (128 rows x 64 cols) each thread does 2 x gload16.
  // source col-chunk pre-swizzled: cswz = (t&7) ^ ((t>>3)&7)
  const int cswz = (t & 7) ^ ((t >> 3) & 7);
  const _Float16* gA = hin + (size_t)(brow + (t >> 3)) * HDIM + cswz * 8;
  const _Float16* gB = W + (size_t)(bcol + (t >> 3)) * HDIM + cswz * 8;
  const int dstw = w << 10;  // wave-uniform LDS dest offset (lane adds l*16)

  auto stageB = [&](int kt, int par) {
    char* d = smem + par * 65536 + 32768 + dstw;
    const _Float16* s = gB + kt * 64;
#pragma unroll
    for (int h = 0; h < 2; ++h) {
      gload16(s + (size_t)(h * 128) * HDIM, d + h * 16384);
      gload16(s + (size_t)(h * 128 + 64) * HDIM, d + h * 16384 + 8192);
    }
  };
  auto stageA = [&](int kt, int par) {
    char* d = smem + par * 65536 + dstw;
    const _Float16* s = gA + kt * 64;
#pragma unroll
    for (int h = 0; h < 2; ++h) {
      gload16(s + (size_t)(h * 128) * HDIM, d + h * 16384);
      gload16(s + (size_t)(h * 128 + 64) * HDIM, d + h * 16384 + 8192);
    }
  };

  // ds_read lane bases; swizzled chunk bytes for ks=0/1 (row&7 == l&7 at every frag row)
  const int cx0 = (((l >> 4)) ^ (l & 7)) << 4;
  const int cx1 = ((4 | (l >> 4)) ^ (l & 7)) << 4;
  const int arow = wm * 16384 + (l & 15) * 128;
  const int brow_b = 32768 + wn * 8192 + (l & 15) * 128;

  // prologue: stage kt0 into buf0
  stageB(0, 0);
  stageA(0, 0);
  asm volatile("s_waitcnt vmcnt(0)" ::: "memory");
  __builtin_amdgcn_s_barrier();

  f16x8 bf[4][2];
  for (int kt = 0; kt < 16; ++kt) {
    const int par = kt & 1;
    const char* bc = smem + par * 65536;
    const bool pf = (kt < 15);
#pragma unroll
    for (int q = 0; q < 4; ++q) {
      f16x8 af[2][2];
      if (q == 0) {
#pragma unroll
        for (int n = 0; n < 4; ++n) {
          bf[n][0] = *(const f16x8*)(bc + brow_b + n * 2048 + cx0);
          bf[n][1] = *(const f16x8*)(bc + brow_b + n * 2048 + cx1);
        }
      }
#pragma unroll
      for (int mm = 0; mm < 2; ++mm) {
        af[mm][0] = *(const f16x8*)(bc + arow + (2 * q + mm) * 2048 + cx0);
        af[mm][1] = *(const f16x8*)(bc + arow + (2 * q + mm) * 2048 + cx1);
      }
      if (q == 0 && pf) stageB(kt + 1, par ^ 1);   // issue early, wait late (3-phase age)
      if (q == 1 && pf) stageA(kt + 1, par ^ 1);   // 2-phase age
      __builtin_amdgcn_s_barrier();
      asm volatile("s_waitcnt lgkmcnt(0)" ::: "memory");
      __builtin_amdgcn_sched_barrier(0);           // rule #18: fence MFMA below the wait
      __builtin_amdgcn_s_setprio(1);
#pragma unroll
      for (int mm = 0; mm < 2; ++mm)
#pragma unroll
        for (int n = 0; n < 4; ++n) {
          acc[2 * q + mm][n] =
              __builtin_amdgcn_mfma_f32_16x16x32_f16(af[mm][0], bf[n][0], acc[2 * q + mm][n], 0, 0, 0);
          acc[2 * q + mm][n] =
              __builtin_amdgcn_mfma_f32_16x16x32_f16(af[mm][1], bf[n][1], acc[2 * q + mm][n], 0, 0, 0);
        }
      __builtin_amdgcn_s_setprio(0);
      if (q == 3 && pf) asm volatile("s_waitcnt vmcnt(0)" ::: "memory");  // next buf landed (per wave)
      __builtin_amdgcn_s_barrier();  // after this barrier all waves' loads/reads are settled
    }
  }

  // ---- epilogue: LN-affine + relu + fp16 store; stats combined in LDS, then 1 atomic/row-val ----
  float* sred = (float*)smem;  // 256 rows x {sum, sumsq}
  sred[t] = 0.f;               // 512 threads cover 512 floats
  __syncthreads();

  float Sf[4], Bf2[4];
#pragma unroll
  for (int n = 0; n < 4; ++n) {
    int col = bcol + wn * 64 + n * 16 + (l & 15);
    Sf[n] = Sfold[col];
    Bf2[n] = bfold[col];
  }
#pragma unroll
  for (int m = 0; m < 8; ++m) {
#pragma unroll
    for (int rg = 0; rg < 4; ++rg) {
      int rloc = wm * 128 + m * 16 + (l >> 4) * 4 + rg;  // C/D: col=lane&15, row=(lane>>4)*4+reg
      int grow = brow + rloc;
      float sum = stats_in[(size_t)grow * 2 + 0];
      float sumsq = stats_in[(size_t)grow * 2 + 1];
      float mean = sum * (1.f / 1024.f);
      float rstd = rsqrtf(sumsq * (1.f / 1024.f) - mean * mean + EPSLN);
      float ps = 0.f, psq = 0.f;
#pragma unroll
      for (int n = 0; n < 4; ++n) {
        int col = bcol + wn * 64 + n * 16 + (l & 15);
        float vv = rstd * (acc[m][n][rg] - mean * Sf[n]) + Bf2[n];
        vv = fmaxf(vv, 0.f);
        hout[(size_t)grow * HDIM + col] = (_Float16)vv;
        ps += vv; psq += vv * vv;
      }
#pragma unroll
      for (int off2 = 1; off2 < 16; off2 <<= 1) {
        ps += __shfl_xor(ps, off2);
        psq += __shfl_xor(psq, off2);
      }
      if ((l & 15) == 0) {
        atomicAdd(&sred[rloc * 2 + 0], ps);
        atomicAdd(&sred[rloc * 2 + 1], psq);
      }
    }
  }
  __syncthreads();
  atomicAdd(&stats_out[(size_t)(brow + (t >> 1)) * 2 + (t & 1)], sred[t]);
}

// ---------------- head: out = sigmoid(rstd*(h8@W'' - mean*S'') + b''), one wave per row ----------------
__global__ __launch_bounds__(512) void head_kernel(
    const _Float16* __restrict__ h8, const float* __restrict__ stats8,
    const float* __restrict__ headW, const float* __restrict__ headAux,
    float* __restrict__ out, int rowBase) {
  int t = threadIdx.x, l = t & 63, w = t >> 6;
  int lrow = blockIdx.x * 8 + w;
  const f16x8* hp = (const f16x8*)(h8 + (size_t)lrow * HDIM) + l * 2;
  f16x8 v0 = hp[0], v1 = hp[1];
  float acc = 0.f;
#pragma unroll
  for (int j = 0; j < 8; ++j) acc += (float)v0[j] * headW[l * 16 + j];
#pragma unroll
  for (int j = 0; j < 8; ++j) acc += (float)v1[j] * headW[l * 16 + 8 + j];
#pragma unroll
  for (int off = 1; off < 64; off <<= 1) acc += __shfl_xor(acc, off);
  if (l == 0) {
    float sum = stats8[lrow * 2 + 0], sumsq = stats8[lrow * 2 + 1];
    float mean = sum * (1.f / 1024.f);
    float rstd = rsqrtf(sumsq * (1.f / 1024.f) - mean * mean + EPSLN);
    float z = rstd * (acc - mean * headAux[0]) + headAux[1];
    out[rowBase + lrow] = 1.f / (1.f + expf(-z));
  }
}

extern "C" void kernel_launch(void* const* d_in, const int* in_sizes, int n_in,
                              void* d_out, int out_size, void* d_ws, size_t ws_size,
                              hipStream_t stream) {
  const float* x      = (const float*)d_in[0];
  const float* stg    = (const float*)d_in[1];
  const float* stb    = (const float*)d_in[2];
  const float* stw    = (const float*)d_in[3];
  const float* stbias = (const float*)d_in[4];
  const float* bg     = (const float*)d_in[5];
  const float* bb     = (const float*)d_in[6];
  const float* bw     = (const float*)d_in[7];
  const float* bbias  = (const float*)d_in[8];
  const float* lg     = (const float*)d_in[9];
  const float* lb     = (const float*)d_in[10];
  const float* lw     = (const float*)d_in[11];
  const float* lbias  = (const float*)d_in[12];
  float* out = (float*)d_out;
  const int B = 65536;
  const int L = 8;

  char* ws = (char*)d_ws;
  size_t off = 0;
  auto carve = [&](size_t bytes) -> char* {
    char* p = ws + off;
    off = (off + bytes + 255) & ~(size_t)255;
    return p;
  };
  _Float16* Wf   = (_Float16*)carve((size_t)L * HDIM * HDIM * 2);
  float* bfold   = (float*)carve((size_t)L * HDIM * 4);
  float* Sfold   = (float*)carve((size_t)L * HDIM * 4);
  float* headW   = (float*)carve((size_t)HDIM * 4);
  float* headAux = (float*)carve(256);
  _Float16* Wst  = (_Float16*)carve((size_t)HDIM * 64 * 2);
  size_t fixed = off;

  // pick largest batch chunk R (power of 2, >=256) whose buffers fit in ws
  int R = B;
  while (R > 256) {
    size_t need = fixed + 2 * ((size_t)R * HDIM * 2 + 256) + ((size_t)9 * R * 2 * 4 + 256)
                  + ((size_t)R * 64 * 2 + 256);
    if (need <= ws_size) break;
    R >>= 1;
  }
  _Float16* hA = (_Float16*)carve((size_t)R * HDIM * 2);
  _Float16* hB = (_Float16*)carve((size_t)R * HDIM * 2);
  float* stats = (float*)carve((size_t)9 * R * 2 * 4);  // 9 slots: h0..h8 (sum,sumsq)
  _Float16* xnb = (_Float16*)carve((size_t)R * 64 * 2);

  fold_blk<<<L * HDIM, 256, 0, stream>>>(bg, bb, bw, bbias, Wf, bfold, Sfold);
  fold_head<<<1, 256, 0, stream>>>(lg, lb, lw, lbias, headW, headAux);
  fold_stem<<<HDIM * 64 / 256, 256, 0, stream>>>(stw, Wst);

  const int nstats = 9 * R * 2;
  for (int c = 0; c < B / R; ++c) {
    int rowBase = c * R;
    zero_f32<<<(nstats + 255) / 256, 256, 0, stream>>>(stats, nstats);
    stem_prep<<<R / 128, 256, 0, stream>>>(x, stg, stb, xnb, rowBase);
    {
      dim3 grid(R / 128, 8);
      stem_gemm<<<grid, 256, 0, stream>>>(xnb, Wst, stbias, hA, stats);
    }
    _Float16* cur = hA;
    _Float16* nxt = hB;
    for (int lyr = 0; lyr < L; ++lyr) {
      int nb = (R / 256) * 4;
      layer_gemm<<<nb, 512, 0, stream>>>(
          cur, stats + (size_t)lyr * R * 2, Wf + (size_t)lyr * HDIM * HDIM,
          bfold + lyr * HDIM, Sfold + lyr * HDIM, nxt, stats + (size_t)(lyr + 1) * R * 2);
      _Float16* tmp = cur; cur = nxt; nxt = tmp;
    }
    head_kernel<<<R / 8, 512, 0, stream>>>(cur, stats + (size_t)8 * R * 2, headW, headAux, out, rowBase);
  }
}

// Round 4
// 1350.938 us; speedup vs baseline: 1.7567x; 1.1070x over previous
//
#include <hip/hip_runtime.h>
#include <hip/hip_bf16.h>
#include <stdint.h>

// DeepFakeDetectionModel: stem LN(26)->Linear(26->1024)->ReLU, 8x [LN->Linear(1024->1024)->ReLU],
// head LN->Linear(1024->1)->sigmoid.  B=65536.
//
// LN folded into weights (W'=gamma*W fp16, S'=sum W', b'=b+beta@W^T); GEMMs run on RAW fp16
// activations; LN affine applied in epilogue from per-row (sum,sumsq) stats.
// R2: 256x256 tile, T2 swizzle (bank conflicts 2.5e7 -> 0), LDS-combined stats.
// R3: stripped intra-tile barriers (our dbuf layout has no intra-tile hazard, unlike HK's
//     half-tile template) -> 1 __syncthreads()/K-tile; stage issued a full tile ahead so the
//     sync's vmcnt(0) drain is pre-satisfied; A-frag reads pipelined one quadrant ahead;
//     XCD chunk swizzle so the 4 col-blocks sharing an A-panel land on one XCD L2.

typedef __attribute__((ext_vector_type(8))) _Float16 f16x8;
typedef __attribute__((ext_vector_type(4))) float f32x4;

#define EPSLN 1e-5f
#define HDIM 1024

__device__ __forceinline__ void gload16(const void* g, void* l) {
  __builtin_amdgcn_global_load_lds(
      (const __attribute__((address_space(1))) unsigned int*)g,
      (__attribute__((address_space(3))) unsigned int*)l, 16, 0, 0);
}

// ---------------- zero stats ----------------
__global__ __launch_bounds__(256) void zero_f32(float* __restrict__ p, int n) {
  int i = blockIdx.x * 256 + threadIdx.x;
  if (i < n) p[i] = 0.f;
}

// ---------------- fold block weights ----------------
__global__ __launch_bounds__(256) void fold_blk(
    const float* __restrict__ bg, const float* __restrict__ bb,
    const float* __restrict__ bw, const float* __restrict__ bbias,
    _Float16* __restrict__ Wf, float* __restrict__ bfold, float* __restrict__ Sfold) {
  int lo = blockIdx.x;            // layer*1024 + o
  int layer = lo >> 10;
  const float* wrow = bw + (size_t)lo * HDIM;
  const float* g = bg + (size_t)layer * HDIM;
  const float* be = bb + (size_t)layer * HDIM;
  _Float16* wout = Wf + (size_t)lo * HDIM;
  int t = threadIdx.x;
  float s = 0.f, acb = 0.f;
  for (int i = t; i < HDIM; i += 256) {
    float wv = wrow[i];
    _Float16 wp = (_Float16)(wv * g[i]);
    wout[i] = wp;
    s += (float)wp;               // S' from ROUNDED weights (consistency with GEMM)
    acb += be[i] * wv;
  }
#pragma unroll
  for (int off = 1; off < 64; off <<= 1) { s += __shfl_xor(s, off); acb += __shfl_xor(acb, off); }
  __shared__ float rs[4], rb[4];
  int l = t & 63, w = t >> 6;
  if (l == 0) { rs[w] = s; rb[w] = acb; }
  __syncthreads();
  if (t == 0) {
    Sfold[lo] = rs[0] + rs[1] + rs[2] + rs[3];
    bfold[lo] = bbias[lo] + rb[0] + rb[1] + rb[2] + rb[3];
  }
}

// ---------------- fold head ----------------
__global__ __launch_bounds__(256) void fold_head(
    const float* __restrict__ lg, const float* __restrict__ lb,
    const float* __restrict__ lw, const float* __restrict__ lbias,
    float* __restrict__ headW, float* __restrict__ headAux) {
  int t = threadIdx.x;
  float s = 0.f, acb = 0.f;
  for (int i = t; i < HDIM; i += 256) {
    float wp = lw[i] * lg[i];
    headW[i] = wp;
    s += wp;
    acb += lb[i] * lw[i];
  }
#pragma unroll
  for (int off = 1; off < 64; off <<= 1) { s += __shfl_xor(s, off); acb += __shfl_xor(acb, off); }
  __shared__ float rs[4], rb[4];
  int l = t & 63, w = t >> 6;
  if (l == 0) { rs[w] = s; rb[w] = acb; }
  __syncthreads();
  if (t == 0) {
    headAux[0] = rs[0] + rs[1] + rs[2] + rs[3];
    headAux[1] = lbias[0] + rb[0] + rb[1] + rb[2] + rb[3];
  }
}

// ---------------- stem weight pad+cast ----------------
__global__ __launch_bounds__(256) void fold_stem(const float* __restrict__ stw,
                                                 _Float16* __restrict__ Wst) {
  int idx = blockIdx.x * 256 + threadIdx.x;   // 1024*64
  int o = idx >> 6, i = idx & 63;
  Wst[idx] = (i < 26) ? (_Float16)stw[o * 26 + i] : (_Float16)0.f;
}

// ---------------- stem prepass: LN(26) -> xn fp16 [rows][64], zero-padded ----------------
__global__ __launch_bounds__(256) void stem_prep(
    const float* __restrict__ x, const float* __restrict__ stg, const float* __restrict__ stb,
    _Float16* __restrict__ xn, int rowBase) {
  __shared__ float xin[128 * 26];
  __shared__ _Float16 xo[128 * 64];
  int t = threadIdx.x;
  const float* src = x + ((size_t)rowBase + (size_t)blockIdx.x * 128) * 26;
  for (int i = t; i < 128 * 26; i += 256) xin[i] = src[i];
  __syncthreads();
  if (t < 128) {
    float m = 0.f;
#pragma unroll
    for (int i = 0; i < 26; ++i) m += xin[t * 26 + i];
    m *= (1.f / 26.f);
    float v = 0.f;
#pragma unroll
    for (int i = 0; i < 26; ++i) { float d = xin[t * 26 + i] - m; v += d * d; }
    float rstd = rsqrtf(v * (1.f / 26.f) + EPSLN);
    _Float16* orow = xo + t * 64;
#pragma unroll
    for (int i = 0; i < 26; ++i)
      orow[i] = (_Float16)((xin[t * 26 + i] - m) * rstd * stg[i] + stb[i]);
#pragma unroll
    for (int i = 26; i < 64; ++i) orow[i] = (_Float16)0.f;
  }
  __syncthreads();
  const float4* s4 = (const float4*)xo;
  float4* d4 = (float4*)(xn + (size_t)blockIdx.x * 128 * 64);
  for (int i = t; i < 1024; i += 256) d4[i] = s4[i];
}

// ---------------- stem GEMM: h0 = relu(xn @ Wst^T + stbias), K=64, + stats ----------------
__global__ __launch_bounds__(256) void stem_gemm(
    const _Float16* __restrict__ xn, const _Float16* __restrict__ Wst,
    const float* __restrict__ stbias, _Float16* __restrict__ hout,
    float* __restrict__ stats_out) {
  __shared__ _Float16 As[128 * 64];
  __shared__ _Float16 Bs[128 * 64];
  const int t = threadIdx.x;
  const int l = t & 63;
  const int w = t >> 6;
  const int wm = w >> 1, wn = w & 1;
  const int brow = blockIdx.x * 128;
  const int bcol = blockIdx.y * 128;

  f32x4 acc[4][4];
#pragma unroll
  for (int i = 0; i < 4; ++i)
#pragma unroll
    for (int j = 0; j < 4; ++j) acc[i][j] = (f32x4){0.f, 0.f, 0.f, 0.f};

  const _Float16* ga = xn + (size_t)(brow + (t >> 3)) * 64 + (t & 7) * 8;
  const _Float16* gb = Wst + (size_t)(bcol + (t >> 3)) * 64 + (t & 7) * 8;
  char* lA = (char*)As + (size_t)w * 1024;
  char* lB = (char*)Bs + (size_t)w * 1024;
#pragma unroll
  for (int q = 0; q < 4; ++q) {
    gload16(ga + (size_t)q * 32 * 64, lA + q * 4096);
    gload16(gb + (size_t)q * 32 * 64, lB + q * 4096);
  }
  __syncthreads();

  const int abyte0 = (wm * 64 + (l & 15)) * 128 + (l >> 4) * 16;
  const int bbyte0 = (wn * 64 + (l & 15)) * 128 + (l >> 4) * 16;
#pragma unroll
  for (int ks = 0; ks < 2; ++ks) {
    f16x8 af[4], bfr[4];
#pragma unroll
    for (int m = 0; m < 4; ++m)
      af[m] = *(const f16x8*)((const char*)As + abyte0 + m * 2048 + ks * 64);
#pragma unroll
    for (int n = 0; n < 4; ++n)
      bfr[n] = *(const f16x8*)((const char*)Bs + bbyte0 + n * 2048 + ks * 64);
#pragma unroll
    for (int m = 0; m < 4; ++m)
#pragma unroll
      for (int n = 0; n < 4; ++n)
        acc[m][n] = __builtin_amdgcn_mfma_f32_16x16x32_f16(af[m], bfr[n], acc[m][n], 0, 0, 0);
  }

  float Bf[4];
#pragma unroll
  for (int n = 0; n < 4; ++n) Bf[n] = stbias[bcol + wn * 64 + n * 16 + (l & 15)];
#pragma unroll
  for (int m = 0; m < 4; ++m) {
#pragma unroll
    for (int rg = 0; rg < 4; ++rg) {
      int lrow = brow + wm * 64 + m * 16 + (l >> 4) * 4 + rg;
      float ps = 0.f, psq = 0.f;
#pragma unroll
      for (int n = 0; n < 4; ++n) {
        int col = bcol + wn * 64 + n * 16 + (l & 15);
        float vv = fmaxf(acc[m][n][rg] + Bf[n], 0.f);
        hout[(size_t)lrow * HDIM + col] = (_Float16)vv;
        ps += vv; psq += vv * vv;
      }
#pragma unroll
      for (int off = 1; off < 16; off <<= 1) {
        ps += __shfl_xor(ps, off);
        psq += __shfl_xor(psq, off);
      }
      if ((l & 15) == 0) {
        atomicAdd(&stats_out[lrow * 2 + 0], ps);
        atomicAdd(&stats_out[lrow * 2 + 1], psq);
      }
    }
  }
}

// ---------------- per-layer fused GEMM, 256x256, 1-sync-per-K-tile pipelined schedule ----------------
// 512 thr = 8 waves (2M x 4N); per-wave 128x64 output = acc[8][4] of 16x16x32 f16 MFMA.
// LDS: 2 K-tile buffers x (A 32KB + B 32KB) = 128KB -> 1 block/CU, 2 waves/SIMD.
// Per K-tile: issue bf+af0 ds_reads, issue next tile's 8 gload_lds (full tile of MFMA ahead of
// the drain), pipeline af reads one quadrant ahead of MFMA, ONE __syncthreads() at tile end
// (its vmcnt(0)/lgkmcnt(0) drain is pre-satisfied by then). No intra-tile barriers: phases read
// a stable buffer, stages write the other one.
__global__ __launch_bounds__(512, 2) void layer_gemm(
    const _Float16* __restrict__ hin, const float* __restrict__ stats_in,
    const _Float16* __restrict__ W, const float* __restrict__ bfold,
    const float* __restrict__ Sfold, _Float16* __restrict__ hout,
    float* __restrict__ stats_out) {
  __shared__ __align__(128) char smem[2 * 65536];  // [par][A 32KB | B 32KB]
  const int t = threadIdx.x;
  const int l = t & 63;
  const int w = t >> 6;
  const int wm = w >> 2, wn = w & 3;
  int bid = blockIdx.x;
  {  // XCD chunk swizzle: give each XCD a contiguous bid range (A-panel groups stay on one L2)
    int nb = gridDim.x;
    if ((nb & 7) == 0) { int cpx = nb >> 3; bid = (bid & 7) * cpx + (bid >> 3); }
  }
  const int brow = (bid >> 2) * 256;   // consecutive bids share the A-panel
  const int bcol = (bid & 3) * 256;

  f32x4 acc[8][4];
#pragma unroll
  for (int i = 0; i < 8; ++i)
#pragma unroll
    for (int j = 0; j < 4; ++j) acc[i][j] = (f32x4){0.f, 0.f, 0.f, 0.f};

  // staging: per half-tile (128 rows x 64 cols) each thread does 2 x gload16.
  // source col-chunk pre-swizzled: cswz = (t&7) ^ ((t>>3)&7)  (T2, rule #21: linear LDS dest)
  const int cswz = (t & 7) ^ ((t >> 3) & 7);
  const _Float16* gA = hin + (size_t)(brow + (t >> 3)) * HDIM + cswz * 8;
  const _Float16* gB = W + (size_t)(bcol + (t >> 3)) * HDIM + cswz * 8;
  const int dstw = w << 10;  // wave-uniform LDS dest offset (lane adds l*16)

  auto stageB = [&](int kt, int par) {
    char* d = smem + par * 65536 + 32768 + dstw;
    const _Float16* s = gB + kt * 64;
#pragma unroll
    for (int h = 0; h < 2; ++h) {
      gload16(s + (size_t)(h * 128) * HDIM, d + h * 16384);
      gload16(s + (size_t)(h * 128 + 64) * HDIM, d + h * 16384 + 8192);
    }
  };
  auto stageA = [&](int kt, int par) {
    char* d = smem + par * 65536 + dstw;
    const _Float16* s = gA + kt * 64;
#pragma unroll
    for (int h = 0; h < 2; ++h) {
      gload16(s + (size_t)(h * 128) * HDIM, d + h * 16384);
      gload16(s + (size_t)(h * 128 + 64) * HDIM, d + h * 16384 + 8192);
    }
  };

  // ds_read lane bases; swizzled chunk bytes for ks=0/1 (row&7 == l&7 at every frag row)
  const int cx0 = (((l >> 4)) ^ (l & 7)) << 4;
  const int cx1 = ((4 | (l >> 4)) ^ (l & 7)) << 4;
  const int arow = wm * 16384 + (l & 15) * 128;
  const int brow_b = 32768 + wn * 8192 + (l & 15) * 128;

#define READ_AF(dst, q)                                                 \
  do {                                                                  \
    dst[0][0] = *(const f16x8*)(bc + arow + (2 * (q)) * 2048 + cx0);    \
    dst[0][1] = *(const f16x8*)(bc + arow + (2 * (q)) * 2048 + cx1);    \
    dst[1][0] = *(const f16x8*)(bc + arow + (2 * (q) + 1) * 2048 + cx0);\
    dst[1][1] = *(const f16x8*)(bc + arow + (2 * (q) + 1) * 2048 + cx1);\
  } while (0)

#define MFMA_Q(src, q)                                                                          \
  do {                                                                                          \
    __builtin_amdgcn_s_setprio(1);                                                              \
    _Pragma("unroll") for (int mm = 0; mm < 2; ++mm) _Pragma("unroll") for (int n = 0; n < 4;   \
                                                                            ++n) {              \
      acc[2 * (q) + mm][n] =                                                                    \
          __builtin_amdgcn_mfma_f32_16x16x32_f16(src[mm][0], bf[n][0], acc[2 * (q) + mm][n], 0, \
                                                 0, 0);                                         \
      acc[2 * (q) + mm][n] =                                                                    \
          __builtin_amdgcn_mfma_f32_16x16x32_f16(src[mm][1], bf[n][1], acc[2 * (q) + mm][n], 0, \
                                                 0, 0);                                         \
    }                                                                                           \
    __builtin_amdgcn_s_setprio(0);                                                              \
  } while (0)

  // prologue: stage kt0 into buf0
  stageB(0, 0);
  stageA(0, 0);
  __syncthreads();

  for (int kt = 0; kt < 16; ++kt) {
    const int par = kt & 1;
    const char* bc = smem + par * 65536;
    f16x8 bf[4][2];
#pragma unroll
    for (int n = 0; n < 4; ++n) {
      bf[n][0] = *(const f16x8*)(bc + brow_b + n * 2048 + cx0);
      bf[n][1] = *(const f16x8*)(bc + brow_b + n * 2048 + cx1);
    }
    f16x8 afA[2][2], afB[2][2];
    READ_AF(afA, 0);
    if (kt < 15) {           // issue next tile's stage a full tile of MFMA ahead of the drain
      stageB(kt + 1, par ^ 1);
      stageA(kt + 1, par ^ 1);
    }
    READ_AF(afB, 1);
    MFMA_Q(afA, 0);
    READ_AF(afA, 2);
    MFMA_Q(afB, 1);
    READ_AF(afB, 3);
    MFMA_Q(afA, 2);
    MFMA_Q(afB, 3);
    __syncthreads();         // vmcnt(0)+lgkmcnt(0)+barrier: both pre-satisfied by now
  }
#undef READ_AF
#undef MFMA_Q

  // ---- epilogue: LN-affine + relu + fp16 store; stats combined in LDS, then 1 atomic/row-val ----
  float* sred = (float*)smem;  // 256 rows x {sum, sumsq}
  sred[t] = 0.f;               // 512 threads cover 512 floats
  __syncthreads();

  float Sf[4], Bf2[4];
#pragma unroll
  for (int n = 0; n < 4; ++n) {
    int col = bcol + wn * 64 + n * 16 + (l & 15);
    Sf[n] = Sfold[col];
    Bf2[n] = bfold[col];
  }
#pragma unroll
  for (int m = 0; m < 8; ++m) {
#pragma unroll
    for (int rg = 0; rg < 4; ++rg) {
      int rloc = wm * 128 + m * 16 + (l >> 4) * 4 + rg;  // C/D: col=lane&15, row=(lane>>4)*4+reg
      int grow = brow + rloc;
      float sum = stats_in[(size_t)grow * 2 + 0];
      float sumsq = stats_in[(size_t)grow * 2 + 1];
      float mean = sum * (1.f / 1024.f);
      float rstd = rsqrtf(sumsq * (1.f / 1024.f) - mean * mean + EPSLN);
      float ps = 0.f, psq = 0.f;
#pragma unroll
      for (int n = 0; n < 4; ++n) {
        int col = bcol + wn * 64 + n * 16 + (l & 15);
        float vv = rstd * (acc[m][n][rg] - mean * Sf[n]) + Bf2[n];
        vv = fmaxf(vv, 0.f);
        hout[(size_t)grow * HDIM + col] = (_Float16)vv;
        ps += vv; psq += vv * vv;
      }
#pragma unroll
      for (int off2 = 1; off2 < 16; off2 <<= 1) {
        ps += __shfl_xor(ps, off2);
        psq += __shfl_xor(psq, off2);
      }
      if ((l & 15) == 0) {
        atomicAdd(&sred[rloc * 2 + 0], ps);
        atomicAdd(&sred[rloc * 2 + 1], psq);
      }
    }
  }
  __syncthreads();
  atomicAdd(&stats_out[(size_t)(brow + (t >> 1)) * 2 + (t & 1)], sred[t]);
}

// ---------------- head: out = sigmoid(rstd*(h8@W'' - mean*S'') + b''), one wave per row ----------------
__global__ __launch_bounds__(512) void head_kernel(
    const _Float16* __restrict__ h8, const float* __restrict__ stats8,
    const float* __restrict__ headW, const float* __restrict__ headAux,
    float* __restrict__ out, int rowBase) {
  int t = threadIdx.x, l = t & 63, w = t >> 6;
  int lrow = blockIdx.x * 8 + w;
  const f16x8* hp = (const f16x8*)(h8 + (size_t)lrow * HDIM) + l * 2;
  f16x8 v0 = hp[0], v1 = hp[1];
  float acc = 0.f;
#pragma unroll
  for (int j = 0; j < 8; ++j) acc += (float)v0[j] * headW[l * 16 + j];
#pragma unroll
  for (int j = 0; j < 8; ++j) acc += (float)v1[j] * headW[l * 16 + 8 + j];
#pragma unroll
  for (int off = 1; off < 64; off <<= 1) acc += __shfl_xor(acc, off);
  if (l == 0) {
    float sum = stats8[lrow * 2 + 0], sumsq = stats8[lrow * 2 + 1];
    float mean = sum * (1.f / 1024.f);
    float rstd = rsqrtf(sumsq * (1.f / 1024.f) - mean * mean + EPSLN);
    float z = rstd * (acc - mean * headAux[0]) + headAux[1];
    out[rowBase + lrow] = 1.f / (1.f + expf(-z));
  }
}

extern "C" void kernel_launch(void* const* d_in, const int* in_sizes, int n_in,
                              void* d_out, int out_size, void* d_ws, size_t ws_size,
                              hipStream_t stream) {
  const float* x      = (const float*)d_in[0];
  const float* stg    = (const float*)d_in[1];
  const float* stb    = (const float*)d_in[2];
  const float* stw    = (const float*)d_in[3];
  const float* stbias = (const float*)d_in[4];
  const float* bg     = (const float*)d_in[5];
  const float* bb     = (const float*)d_in[6];
  const float* bw     = (const float*)d_in[7];
  const float* bbias  = (const float*)d_in[8];
  const float* lg     = (const float*)d_in[9];
  const float* lb     = (const float*)d_in[10];
  const float* lw     = (const float*)d_in[11];
  const float* lbias  = (const float*)d_in[12];
  float* out = (float*)d_out;
  const int B = 65536;
  const int L = 8;

  char* ws = (char*)d_ws;
  size_t off = 0;
  auto carve = [&](size_t bytes) -> char* {
    char* p = ws + off;
    off = (off + bytes + 255) & ~(size_t)255;
    return p;
  };
  _Float16* Wf   = (_Float16*)carve((size_t)L * HDIM * HDIM * 2);
  float* bfold   = (float*)carve((size_t)L * HDIM * 4);
  float* Sfold   = (float*)carve((size_t)L * HDIM * 4);
  float* headW   = (float*)carve((size_t)HDIM * 4);
  float* headAux = (float*)carve(256);
  _Float16* Wst  = (_Float16*)carve((size_t)HDIM * 64 * 2);
  size_t fixed = off;

  // pick largest batch chunk R (power of 2, >=256) whose buffers fit in ws
  int R = B;
  while (R > 256) {
    size_t need = fixed + 2 * ((size_t)R * HDIM * 2 + 256) + ((size_t)9 * R * 2 * 4 + 256)
                  + ((size_t)R * 64 * 2 + 256);
    if (need <= ws_size) break;
    R >>= 1;
  }
  _Float16* hA = (_Float16*)carve((size_t)R * HDIM * 2);
  _Float16* hB = (_Float16*)carve((size_t)R * HDIM * 2);
  float* stats = (float*)carve((size_t)9 * R * 2 * 4);  // 9 slots: h0..h8 (sum,sumsq)
  _Float16* xnb = (_Float16*)carve((size_t)R * 64 * 2);

  fold_blk<<<L * HDIM, 256, 0, stream>>>(bg, bb, bw, bbias, Wf, bfold, Sfold);
  fold_head<<<1, 256, 0, stream>>>(lg, lb, lw, lbias, headW, headAux);
  fold_stem<<<HDIM * 64 / 256, 256, 0, stream>>>(stw, Wst);

  const int nstats = 9 * R * 2;
  for (int c = 0; c < B / R; ++c) {
    int rowBase = c * R;
    zero_f32<<<(nstats + 255) / 256, 256, 0, stream>>>(stats, nstats);
    stem_prep<<<R / 128, 256, 0, stream>>>(x, stg, stb, xnb, rowBase);
    {
      dim3 grid(R / 128, 8);
      stem_gemm<<<grid, 256, 0, stream>>>(xnb, Wst, stbias, hA, stats);
    }
    _Float16* cur = hA;
    _Float16* nxt = hB;
    for (int lyr = 0; lyr < L; ++lyr) {
      int nb = (R / 256) * 4;
      layer_gemm<<<nb, 512, 0, stream>>>(
          cur, stats + (size_t)lyr * R * 2, Wf + (size_t)lyr * HDIM * HDIM,
          bfold + lyr * HDIM, Sfold + lyr * HDIM, nxt, stats + (size_t)(lyr + 1) * R * 2);
      _Float16* tmp = cur; cur = nxt; nxt = tmp;
    }
    head_kernel<<<R / 8, 512, 0, stream>>>(cur, stats + (size_t)8 * R * 2, headW, headAux, out, rowBase);
  }
}